// Round 11
// baseline (308.199 us; speedup 1.0000x reference)
//
#include <hip/hip_runtime.h>

#define N_NODES 50000
#define NEG_SLOPE 0.2f

typedef short s8v __attribute__((ext_vector_type(8)));
typedef float f4v __attribute__((ext_vector_type(4)));

// ---- bf16 helpers (RNE) ---------------------------------------------------
__device__ __forceinline__ ushort f2bf(float f) {
  union { float f; unsigned u; } v; v.f = f;
  return (ushort)((v.u + 0x7FFFu + ((v.u >> 16) & 1u)) >> 16);
}
__device__ __forceinline__ float bf2f(ushort h) {
  union { unsigned u; float f; } v; v.u = ((unsigned)h) << 16;
  return v.f;
}

// ---- both weight transposes in one kernel ---------------------------------
__global__ void convT2_kernel(const float* __restrict__ W0, ushort* __restrict__ W0T,
                              const float* __restrict__ W1, ushort* __restrict__ W1T) {
  int i = blockIdx.x * blockDim.x + threadIdx.x;
  if (i < 32768) {
    int r = i >> 8, c = i & 255;           // W0: R=128, C=256
    W0T[c * 128 + r] = f2bf(W0[i]);
  } else {
    int j = i - 32768;
    int r = j >> 7, c = j & 127;           // W1: R=256, C=128
    W1T[c * 256 + r] = f2bf(W1[j]);
  }
}

// ---- MFMA GEMM, 64M x 128N tile + direct-store attention scores -----------
// R8/R10-proven structure — DO NOT restructure (R9's rewrite was flaky).
template <int HEADS, bool AF32>
__global__ __launch_bounds__(256) void gemm_mfma(
    const void* __restrict__ Av, const ushort* __restrict__ BT,
    ushort* __restrict__ C, int M, int N, int K,
    const float* __restrict__ a_src, const float* __restrict__ a_dst,
    float* __restrict__ ss, float* __restrict__ sd) {
  __shared__ ushort As[64][136];   // +8 pad: 16B-aligned, 2-way banks (free)
  __shared__ ushort Bs[128][136];
  const int tid = threadIdx.x;
  const int w = tid >> 6, lane = tid & 63;
  const int q = lane >> 4, r16 = lane & 15;
  const int n0 = blockIdx.x * 128, m0 = blockIdx.y * 64;
  f4v acc[8] = {};
  for (int kc = 0; kc < K; kc += 128) {
    // stage A tile 64x128
#pragma unroll
    for (int i = 0; i < 4; ++i) {
      int c = tid + 256 * i;
      int row = c >> 4, ko = (c & 15) * 8;
      int gm = m0 + row;
      s8v va = {};
      if (gm < M) {
        if (AF32) {
          const float* A = (const float*)Av;
          float4 f0 = *reinterpret_cast<const float4*>(&A[(size_t)gm * K + kc + ko]);
          float4 f1 = *reinterpret_cast<const float4*>(&A[(size_t)gm * K + kc + ko + 4]);
          va[0] = (short)f2bf(f0.x); va[1] = (short)f2bf(f0.y);
          va[2] = (short)f2bf(f0.z); va[3] = (short)f2bf(f0.w);
          va[4] = (short)f2bf(f1.x); va[5] = (short)f2bf(f1.y);
          va[6] = (short)f2bf(f1.z); va[7] = (short)f2bf(f1.w);
        } else {
          const ushort* A = (const ushort*)Av;
          va = *reinterpret_cast<const s8v*>(&A[(size_t)gm * K + kc + ko]);
        }
      }
      *reinterpret_cast<s8v*>(&As[row][ko]) = va;
    }
    // stage B tile 128x128
#pragma unroll
    for (int i = 0; i < 8; ++i) {
      int c = tid + 256 * i;
      int row = c >> 4, ko = (c & 15) * 8;
      s8v vb = *reinterpret_cast<const s8v*>(&BT[(size_t)(n0 + row) * K + kc + ko]);
      *reinterpret_cast<s8v*>(&Bs[row][ko]) = vb;
    }
    __syncthreads();
#pragma unroll
    for (int ks = 0; ks < 4; ++ks) {
      s8v af = *reinterpret_cast<const s8v*>(&As[w * 16 + r16][ks * 32 + q * 8]);
#pragma unroll
      for (int nt = 0; nt < 8; ++nt) {
        s8v bf = *reinterpret_cast<const s8v*>(&Bs[nt * 16 + r16][ks * 32 + q * 8]);
        acc[nt] = __builtin_amdgcn_mfma_f32_16x16x32_bf16(af, bf, acc[nt], 0, 0, 0);
      }
    }
    __syncthreads();
  }
  // C store: D row=(lane>>4)*4+reg, col=lane&15
#pragma unroll
  for (int nt = 0; nt < 8; ++nt)
#pragma unroll
    for (int r = 0; r < 4; ++r) {
      int gm = m0 + w * 16 + q * 4 + r;
      if (gm < M) C[(size_t)gm * N + n0 + nt * 16 + r16] = f2bf(acc[nt][r]);
    }
  // scores: block covers the whole head -> exact sums, direct store
  const int head = n0 >> 7;
  float ps[4] = {0.f, 0.f, 0.f, 0.f}, pd[4] = {0.f, 0.f, 0.f, 0.f};
#pragma unroll
  for (int nt = 0; nt < 8; ++nt) {
    int n = n0 + nt * 16 + r16;
    float as = a_src[n], ad = a_dst[n];
#pragma unroll
    for (int r = 0; r < 4; ++r) {
      ps[r] = fmaf(acc[nt][r], as, ps[r]);
      pd[r] = fmaf(acc[nt][r], ad, pd[r]);
    }
  }
#pragma unroll
  for (int off = 1; off < 16; off <<= 1) {
#pragma unroll
    for (int r = 0; r < 4; ++r) {
      ps[r] += __shfl_xor(ps[r], off);
      pd[r] += __shfl_xor(pd[r], off);
    }
  }
  if (r16 == 0) {
#pragma unroll
    for (int r = 0; r < 4; ++r) {
      int gm = m0 + w * 16 + q * 4 + r;
      if (gm < M) {
        ss[gm * HEADS + head] = ps[r];
        sd[gm * HEADS + head] = pd[r];
      }
    }
  }
}

// ------------- CSR build: hist(+u16 rank) -> scan1 -> scan23 -> scatter -----
__global__ void hist_kernel(const int* __restrict__ ei, int E, int Etot,
                            int* __restrict__ counts, ushort* __restrict__ rank) {
  int e = blockIdx.x * blockDim.x + threadIdx.x;
  if (e >= Etot) return;
  int d = (e < E) ? ei[E + e] : (e - E);
  rank[e] = (ushort)atomicAdd(&counts[d], 1);  // degree << 65536
}

__global__ __launch_bounds__(1024) void scan1_kernel(const int* __restrict__ counts,
                                                     int* __restrict__ partial,
                                                     int* __restrict__ blocksums, int n) {
  __shared__ int tmp[1024];
  int i = blockIdx.x * 1024 + threadIdx.x;
  int v = (i < n) ? counts[i] : 0;
  tmp[threadIdx.x] = v;
  __syncthreads();
  for (int off = 1; off < 1024; off <<= 1) {
    int t = (threadIdx.x >= off) ? tmp[threadIdx.x - off] : 0;
    __syncthreads();
    tmp[threadIdx.x] += t;
    __syncthreads();
  }
  if (i < n) partial[i] = tmp[threadIdx.x];
  if (threadIdx.x == 1023) blocksums[blockIdx.x] = tmp[1023];
}

__global__ void scan23_kernel(const int* __restrict__ partial,
                              const int* __restrict__ blocksums,
                              int* __restrict__ rowptr, int n, int nb) {
  __shared__ int sb[64];
  int t = threadIdx.x;
  if (t < 64) {
    int v = (t < nb) ? blocksums[t] : 0;
#pragma unroll
    for (int off = 1; off < 64; off <<= 1) {
      int u = __shfl_up(v, off);
      if ((t & 63) >= off) v += u;
    }
    sb[t] = v;
  }
  __syncthreads();
  int i = blockIdx.x * blockDim.x + t;
  if (i == 0) rowptr[0] = 0;
  if (i < n) {
    int b = i >> 10;
    int add = (b > 0) ? sb[b - 1] : 0;
    rowptr[i + 1] = partial[i] + add;
  }
}

// scatter: no atomics; ONE 4B random write per edge (s | d<<16, both <65536)
__global__ void scatter_kernel(const int* __restrict__ ei, int E, int Etot,
                               const int* __restrict__ rowptr,
                               const ushort* __restrict__ rank,
                               unsigned* __restrict__ csrSD) {
  int e = blockIdx.x * blockDim.x + threadIdx.x;
  if (e >= Etot) return;
  int s, d;
  if (e < E) { s = ei[e]; d = ei[E + e]; } else { s = d = e - E; }
  csrSD[rowptr[d] + (int)rank[e]] = (unsigned)s | ((unsigned)d << 16);
}

// ---- layer-0 aggregation: head-split (blockIdx.y), inline edge weights ----
// wave = (node, head); 256B row-half = 2 full cache lines; per-phase working
// set 12.8 MB. 8-deep MLP (per-edge bytes halved vs R10). Scores fp32 inline.
__global__ __launch_bounds__(256) void agg0_kernel(
    const ushort* __restrict__ h0,   // [N,256] bf16
    const float* __restrict__ ss, const float* __restrict__ sd,  // [N,2]
    const int* __restrict__ rowptr, const unsigned* __restrict__ csrSD,
    const float* __restrict__ b0, ushort* __restrict__ hE) {
  const int n = blockIdx.x * 4 + (threadIdx.x >> 6);
  const int hd = blockIdx.y;           // 0 / 1
  const int t = threadIdx.x & 63;
  const int ch = hd * 128 + t * 2;
  const float sdn = sd[n * 2 + hd];
  float a0 = 0.f, a1 = 0.f, den = 0.f;
  int p = rowptr[n];
  const int p1 = rowptr[n + 1];
  for (; p + 8 <= p1; p += 8) {  // 8 row-halves in flight per wave
    int s[8];
#pragma unroll
    for (int j = 0; j < 8; ++j) s[j] = (int)(csrSD[p + j] & 0xFFFFu);
    ushort2 v[8];
#pragma unroll
    for (int j = 0; j < 8; ++j)
      v[j] = *reinterpret_cast<const ushort2*>(&h0[(size_t)s[j] * 256 + ch]);
    float w[8];
#pragma unroll
    for (int j = 0; j < 8; ++j) {
      float e = ss[s[j] * 2 + hd] + sdn;
      e = (e > 0.f) ? e : NEG_SLOPE * e;
      w[j] = __expf(e);
    }
#pragma unroll
    for (int j = 0; j < 8; ++j) {
      den += w[j];
      a0 = fmaf(w[j], bf2f(v[j].x), a0);
      a1 = fmaf(w[j], bf2f(v[j].y), a1);
    }
  }
  for (; p < p1; ++p) {
    const int sj = (int)(csrSD[p] & 0xFFFFu);
    float e = ss[sj * 2 + hd] + sdn;
    e = (e > 0.f) ? e : NEG_SLOPE * e;
    const float wj = __expf(e);
    const ushort2 vj = *reinterpret_cast<const ushort2*>(&h0[(size_t)sj * 256 + ch]);
    den += wj;
    a0 = fmaf(wj, bf2f(vj.x), a0);
    a1 = fmaf(wj, bf2f(vj.y), a1);
  }
  const float inv = 1.f / den;
  const float2 bv = *reinterpret_cast<const float2*>(&b0[ch]);
  float o0 = fmaf(a0, inv, bv.x), o1 = fmaf(a1, inv, bv.y);
  o0 = (o0 > 0.f) ? o0 : (__expf(o0) - 1.f);
  o1 = (o1 > 0.f) ? o1 : (__expf(o1) - 1.f);
  ushort2 ov; ov.x = f2bf(o0); ov.y = f2bf(o1);
  *reinterpret_cast<ushort2*>(&hE[(size_t)n * 256 + ch]) = ov;
}

// ---- layer-1 aggregation: inline edge weights + bias + residual -----------
__global__ __launch_bounds__(256) void agg1_kernel(
    const ushort* __restrict__ h1,   // [N,128] bf16
    const float* __restrict__ ss, const float* __restrict__ sd,  // [N]
    const int* __restrict__ rowptr, const unsigned* __restrict__ csrSD,
    const float* __restrict__ b1, const float2* __restrict__ x,
    float2* __restrict__ out) {
  const int n = blockIdx.x * 4 + (threadIdx.x >> 6);
  const int t = threadIdx.x & 63;
  const float sdn = sd[n];
  float a0 = 0.f, a1 = 0.f, den = 0.f;
  int p = rowptr[n];
  const int p1 = rowptr[n + 1];
  for (; p + 4 <= p1; p += 4) {
    int s[4];
#pragma unroll
    for (int j = 0; j < 4; ++j) s[j] = (int)(csrSD[p + j] & 0xFFFFu);
    ushort2 v[4];
#pragma unroll
    for (int j = 0; j < 4; ++j)
      v[j] = *reinterpret_cast<const ushort2*>(&h1[(size_t)s[j] * 128 + t * 2]);
    float w[4];
#pragma unroll
    for (int j = 0; j < 4; ++j) {
      float e = ss[s[j]] + sdn;
      e = (e > 0.f) ? e : NEG_SLOPE * e;
      w[j] = __expf(e);
    }
#pragma unroll
    for (int j = 0; j < 4; ++j) {
      den += w[j];
      a0 = fmaf(w[j], bf2f(v[j].x), a0);
      a1 = fmaf(w[j], bf2f(v[j].y), a1);
    }
  }
  for (; p < p1; ++p) {
    const int sj = (int)(csrSD[p] & 0xFFFFu);
    float e = ss[sj] + sdn;
    e = (e > 0.f) ? e : NEG_SLOPE * e;
    const float wj = __expf(e);
    const ushort2 vj = *reinterpret_cast<const ushort2*>(&h1[(size_t)sj * 128 + t * 2]);
    den += wj;
    a0 = fmaf(wj, bf2f(vj.x), a0);
    a1 = fmaf(wj, bf2f(vj.y), a1);
  }
  const float inv = 1.f / den;
  const float2 bv = reinterpret_cast<const float2*>(b1)[t];
  const float2 xv = x[(size_t)n * 64 + t];
  out[(size_t)n * 64 + t] =
      make_float2(xv.x + fmaf(a0, inv, bv.x), xv.y + fmaf(a1, inv, bv.y));
}

extern "C" void kernel_launch(void* const* d_in, const int* in_sizes, int n_in,
                              void* d_out, int out_size, void* d_ws, size_t ws_size,
                              hipStream_t stream) {
  const float* x      = (const float*)d_in[0];
  const float* W0     = (const float*)d_in[1];
  const float* a_src0 = (const float*)d_in[2];
  const float* a_dst0 = (const float*)d_in[3];
  const float* b0     = (const float*)d_in[4];
  const float* W1     = (const float*)d_in[5];
  const float* a_src1 = (const float*)d_in[6];
  const float* a_dst1 = (const float*)d_in[7];
  const float* b1     = (const float*)d_in[8];
  const int*   ei     = (const int*)d_in[9];
  const int E = in_sizes[9] / 2;
  const int Etot = E + N_NODES;
  float* out = (float*)d_out;
  (void)n_in; (void)out_size; (void)ws_size;

  char* ws = (char*)d_ws;
  size_t off = 0;
  auto alloc = [&](size_t bytes) -> char* {
    char* p = ws + off;
    off += (bytes + 255) & ~(size_t)255;
    return p;
  };
  ushort* h0b  = (ushort*)alloc((size_t)N_NODES * 256 * 2);
  ushort* hEb  = (ushort*)alloc((size_t)N_NODES * 256 * 2);
  ushort* h1b  = (ushort*)alloc((size_t)N_NODES * 128 * 2);
  ushort* W0T  = (ushort*)alloc((size_t)256 * 128 * 2);
  ushort* W1T  = (ushort*)alloc((size_t)128 * 256 * 2);
  int* counts  = (int*)alloc((size_t)N_NODES * 4);      // zero-init below
  float* ss0   = (float*)alloc((size_t)N_NODES * 2 * 4);  // direct-stored
  float* sd0   = (float*)alloc((size_t)N_NODES * 2 * 4);
  float* ss1   = (float*)alloc((size_t)N_NODES * 4);
  float* sd1   = (float*)alloc((size_t)N_NODES * 4);
  int* rowptr  = (int*)alloc((size_t)(N_NODES + 1) * 4);
  int* partial = (int*)alloc((size_t)N_NODES * 4);
  int* bsums   = (int*)alloc((size_t)64 * 4);
  ushort* rank = (ushort*)alloc((size_t)Etot * 2);
  unsigned* csrSD = (unsigned*)alloc((size_t)Etot * 4);

  hipMemsetAsync(counts, 0, (size_t)N_NODES * 4, stream);

  // ---- prep: weight transposes (one kernel) ----
  convT2_kernel<<<65536 / 256, 256, 0, stream>>>(W0, W0T, W1, W1T);

  // ---- CSR build (shared by both layers) ----
  const int nblk = (N_NODES + 1023) / 1024;  // 49
  hist_kernel<<<(Etot + 255) / 256, 256, 0, stream>>>(ei, E, Etot, counts, rank);
  scan1_kernel<<<nblk, 1024, 0, stream>>>(counts, partial, bsums, N_NODES);
  scan23_kernel<<<(N_NODES + 255) / 256, 256, 0, stream>>>(partial, bsums, rowptr,
                                                           N_NODES, nblk);
  scatter_kernel<<<(Etot + 255) / 256, 256, 0, stream>>>(ei, E, Etot, rowptr, rank, csrSD);

  // ---- layer 0 (x converted fp32->bf16 inside gemm staging) ----
  dim3 g0(2, (N_NODES + 63) / 64);
  gemm_mfma<2, true><<<g0, 256, 0, stream>>>(x, W0T, h0b, N_NODES, 256, 128,
                                             a_src0, a_dst0, ss0, sd0);
  dim3 ga0(N_NODES / 4, 2);
  agg0_kernel<<<ga0, 256, 0, stream>>>(h0b, ss0, sd0, rowptr, csrSD, b0, hEb);

  // ---- layer 1 ----
  dim3 g1(1, (N_NODES + 63) / 64);
  gemm_mfma<1, false><<<g1, 256, 0, stream>>>(hEb, W1T, h1b, N_NODES, 128, 256,
                                              a_src1, a_dst1, ss1, sd1);
  agg1_kernel<<<N_NODES / 4, 256, 0, stream>>>(h1b, ss1, sd1, rowptr, csrSD, b1,
                                               (const float2*)x, (float2*)out);
}

// Round 12
// 288.711 us; speedup vs baseline: 1.0675x; 1.0675x over previous
//
#include <hip/hip_runtime.h>

#define N_NODES 50000
#define NEG_SLOPE 0.2f

typedef short s8v __attribute__((ext_vector_type(8)));
typedef float f4v __attribute__((ext_vector_type(4)));

// ---- bf16 helpers (RNE) ---------------------------------------------------
__device__ __forceinline__ ushort f2bf(float f) {
  union { float f; unsigned u; } v; v.f = f;
  return (ushort)((v.u + 0x7FFFu + ((v.u >> 16) & 1u)) >> 16);
}
__device__ __forceinline__ float bf2f(ushort h) {
  union { unsigned u; float f; } v; v.u = ((unsigned)h) << 16;
  return v.f;
}

// ---- both weight transposes in one kernel ---------------------------------
__global__ void convT2_kernel(const float* __restrict__ W0, ushort* __restrict__ W0T,
                              const float* __restrict__ W1, ushort* __restrict__ W1T) {
  int i = blockIdx.x * blockDim.x + threadIdx.x;
  if (i < 32768) {
    int r = i >> 8, c = i & 255;           // W0: R=128, C=256
    W0T[c * 128 + r] = f2bf(W0[i]);
  } else {
    int j = i - 32768;
    int r = j >> 7, c = j & 127;           // W1: R=256, C=128
    W1T[c * 256 + r] = f2bf(W1[j]);
  }
}

// ---- MFMA GEMM, 64M x 128N tile + direct-store attention scores -----------
// R8/R10-proven structure — DO NOT restructure (R9's rewrite was flaky).
template <int HEADS, bool AF32>
__global__ __launch_bounds__(256) void gemm_mfma(
    const void* __restrict__ Av, const ushort* __restrict__ BT,
    ushort* __restrict__ C, int M, int N, int K,
    const float* __restrict__ a_src, const float* __restrict__ a_dst,
    float* __restrict__ ss, float* __restrict__ sd) {
  __shared__ ushort As[64][136];   // +8 pad: 16B-aligned, 2-way banks (free)
  __shared__ ushort Bs[128][136];
  const int tid = threadIdx.x;
  const int w = tid >> 6, lane = tid & 63;
  const int q = lane >> 4, r16 = lane & 15;
  const int n0 = blockIdx.x * 128, m0 = blockIdx.y * 64;
  f4v acc[8] = {};
  for (int kc = 0; kc < K; kc += 128) {
    // stage A tile 64x128
#pragma unroll
    for (int i = 0; i < 4; ++i) {
      int c = tid + 256 * i;
      int row = c >> 4, ko = (c & 15) * 8;
      int gm = m0 + row;
      s8v va = {};
      if (gm < M) {
        if (AF32) {
          const float* A = (const float*)Av;
          float4 f0 = *reinterpret_cast<const float4*>(&A[(size_t)gm * K + kc + ko]);
          float4 f1 = *reinterpret_cast<const float4*>(&A[(size_t)gm * K + kc + ko + 4]);
          va[0] = (short)f2bf(f0.x); va[1] = (short)f2bf(f0.y);
          va[2] = (short)f2bf(f0.z); va[3] = (short)f2bf(f0.w);
          va[4] = (short)f2bf(f1.x); va[5] = (short)f2bf(f1.y);
          va[6] = (short)f2bf(f1.z); va[7] = (short)f2bf(f1.w);
        } else {
          const ushort* A = (const ushort*)Av;
          va = *reinterpret_cast<const s8v*>(&A[(size_t)gm * K + kc + ko]);
        }
      }
      *reinterpret_cast<s8v*>(&As[row][ko]) = va;
    }
    // stage B tile 128x128
#pragma unroll
    for (int i = 0; i < 8; ++i) {
      int c = tid + 256 * i;
      int row = c >> 4, ko = (c & 15) * 8;
      s8v vb = *reinterpret_cast<const s8v*>(&BT[(size_t)(n0 + row) * K + kc + ko]);
      *reinterpret_cast<s8v*>(&Bs[row][ko]) = vb;
    }
    __syncthreads();
#pragma unroll
    for (int ks = 0; ks < 4; ++ks) {
      s8v af = *reinterpret_cast<const s8v*>(&As[w * 16 + r16][ks * 32 + q * 8]);
#pragma unroll
      for (int nt = 0; nt < 8; ++nt) {
        s8v bf = *reinterpret_cast<const s8v*>(&Bs[nt * 16 + r16][ks * 32 + q * 8]);
        acc[nt] = __builtin_amdgcn_mfma_f32_16x16x32_bf16(af, bf, acc[nt], 0, 0, 0);
      }
    }
    __syncthreads();
  }
  // C store: D row=(lane>>4)*4+reg, col=lane&15
#pragma unroll
  for (int nt = 0; nt < 8; ++nt)
#pragma unroll
    for (int r = 0; r < 4; ++r) {
      int gm = m0 + w * 16 + q * 4 + r;
      if (gm < M) C[(size_t)gm * N + n0 + nt * 16 + r16] = f2bf(acc[nt][r]);
    }
  // scores: block covers the whole head -> exact sums, direct store
  const int head = n0 >> 7;
  float ps[4] = {0.f, 0.f, 0.f, 0.f}, pd[4] = {0.f, 0.f, 0.f, 0.f};
#pragma unroll
  for (int nt = 0; nt < 8; ++nt) {
    int n = n0 + nt * 16 + r16;
    float as = a_src[n], ad = a_dst[n];
#pragma unroll
    for (int r = 0; r < 4; ++r) {
      ps[r] = fmaf(acc[nt][r], as, ps[r]);
      pd[r] = fmaf(acc[nt][r], ad, pd[r]);
    }
  }
#pragma unroll
  for (int off = 1; off < 16; off <<= 1) {
#pragma unroll
    for (int r = 0; r < 4; ++r) {
      ps[r] += __shfl_xor(ps[r], off);
      pd[r] += __shfl_xor(pd[r], off);
    }
  }
  if (r16 == 0) {
#pragma unroll
    for (int r = 0; r < 4; ++r) {
      int gm = m0 + w * 16 + q * 4 + r;
      if (gm < M) {
        ss[gm * HEADS + head] = ps[r];
        sd[gm * HEADS + head] = pd[r];
      }
    }
  }
}

// ------------- CSR build: hist(+u16 rank) -> scan1 -> scan23 -> scatter -----
__global__ void hist_kernel(const int* __restrict__ ei, int E, int Etot,
                            int* __restrict__ counts, ushort* __restrict__ rank) {
  int e = blockIdx.x * blockDim.x + threadIdx.x;
  if (e >= Etot) return;
  int d = (e < E) ? ei[E + e] : (e - E);
  rank[e] = (ushort)atomicAdd(&counts[d], 1);  // degree << 65536
}

__global__ __launch_bounds__(1024) void scan1_kernel(const int* __restrict__ counts,
                                                     int* __restrict__ partial,
                                                     int* __restrict__ blocksums, int n) {
  __shared__ int tmp[1024];
  int i = blockIdx.x * 1024 + threadIdx.x;
  int v = (i < n) ? counts[i] : 0;
  tmp[threadIdx.x] = v;
  __syncthreads();
  for (int off = 1; off < 1024; off <<= 1) {
    int t = (threadIdx.x >= off) ? tmp[threadIdx.x - off] : 0;
    __syncthreads();
    tmp[threadIdx.x] += t;
    __syncthreads();
  }
  if (i < n) partial[i] = tmp[threadIdx.x];
  if (threadIdx.x == 1023) blocksums[blockIdx.x] = tmp[1023];
}

__global__ void scan23_kernel(const int* __restrict__ partial,
                              const int* __restrict__ blocksums,
                              int* __restrict__ rowptr, int n, int nb) {
  __shared__ int sb[64];
  int t = threadIdx.x;
  if (t < 64) {
    int v = (t < nb) ? blocksums[t] : 0;
#pragma unroll
    for (int off = 1; off < 64; off <<= 1) {
      int u = __shfl_up(v, off);
      if ((t & 63) >= off) v += u;
    }
    sb[t] = v;
  }
  __syncthreads();
  int i = blockIdx.x * blockDim.x + t;
  if (i == 0) rowptr[0] = 0;
  if (i < n) {
    int b = i >> 10;
    int add = (b > 0) ? sb[b - 1] : 0;
    rowptr[i + 1] = partial[i] + add;
  }
}

// scatter: no atomics; ONE 4B random write per edge (s | d<<16, both <65536)
__global__ void scatter_kernel(const int* __restrict__ ei, int E, int Etot,
                               const int* __restrict__ rowptr,
                               const ushort* __restrict__ rank,
                               unsigned* __restrict__ csrSD) {
  int e = blockIdx.x * blockDim.x + threadIdx.x;
  if (e >= Etot) return;
  int s, d;
  if (e < E) { s = ei[e]; d = ei[E + e]; } else { s = d = e - E; }
  csrSD[rowptr[d] + (int)rank[e]] = (unsigned)s | ((unsigned)d << 16);
}

// ---- layer-0 aggregation: whole-row wave (R10 structure), inline weights --
// wave = dst node; lanes 0-31 head0, 32-63 head1; 8B/lane (ushort4).
// w = exp(leakyrelu(ss[s]+sd[n])) computed per lane from L2-resident scores.
__global__ __launch_bounds__(256) void agg0_kernel(
    const ushort* __restrict__ h0,   // [N,256] bf16
    const float* __restrict__ ss, const float* __restrict__ sd,  // [N,2]
    const int* __restrict__ rowptr, const unsigned* __restrict__ csrSD,
    const float* __restrict__ b0, ushort* __restrict__ hE) {
  const int n = blockIdx.x * 4 + (threadIdx.x >> 6);
  const int t = threadIdx.x & 63;
  const int hd = t >> 5;
  const float sdn = sd[n * 2 + hd];
  float a0 = 0.f, a1 = 0.f, a2 = 0.f, a3 = 0.f, den = 0.f;
  int p = rowptr[n];
  const int p1 = rowptr[n + 1];
  for (; p + 4 <= p1; p += 4) {  // 4 rows in flight per wave
    int s[4];
#pragma unroll
    for (int j = 0; j < 4; ++j) s[j] = (int)(csrSD[p + j] & 0xFFFFu);
    ushort4 v[4];
#pragma unroll
    for (int j = 0; j < 4; ++j)
      v[j] = *reinterpret_cast<const ushort4*>(&h0[(size_t)s[j] * 256 + t * 4]);
    float w[4];
#pragma unroll
    for (int j = 0; j < 4; ++j) {
      float e = ss[s[j] * 2 + hd] + sdn;
      e = (e > 0.f) ? e : NEG_SLOPE * e;
      w[j] = __expf(e);
    }
#pragma unroll
    for (int j = 0; j < 4; ++j) {
      den += w[j];
      a0 = fmaf(w[j], bf2f(v[j].x), a0);
      a1 = fmaf(w[j], bf2f(v[j].y), a1);
      a2 = fmaf(w[j], bf2f(v[j].z), a2);
      a3 = fmaf(w[j], bf2f(v[j].w), a3);
    }
  }
  for (; p < p1; ++p) {
    const int sj = (int)(csrSD[p] & 0xFFFFu);
    float e = ss[sj * 2 + hd] + sdn;
    e = (e > 0.f) ? e : NEG_SLOPE * e;
    const float wj = __expf(e);
    const ushort4 vj = *reinterpret_cast<const ushort4*>(&h0[(size_t)sj * 256 + t * 4]);
    den += wj;
    a0 = fmaf(wj, bf2f(vj.x), a0); a1 = fmaf(wj, bf2f(vj.y), a1);
    a2 = fmaf(wj, bf2f(vj.z), a2); a3 = fmaf(wj, bf2f(vj.w), a3);
  }
  const float inv = 1.f / den;
  const float4 bv = reinterpret_cast<const float4*>(b0)[t];
  float o[4] = {fmaf(a0, inv, bv.x), fmaf(a1, inv, bv.y),
                fmaf(a2, inv, bv.z), fmaf(a3, inv, bv.w)};
#pragma unroll
  for (int i = 0; i < 4; ++i) o[i] = (o[i] > 0.f) ? o[i] : (__expf(o[i]) - 1.f);
  ushort4 ov; ov.x = f2bf(o[0]); ov.y = f2bf(o[1]); ov.z = f2bf(o[2]); ov.w = f2bf(o[3]);
  *reinterpret_cast<ushort4*>(&hE[(size_t)n * 256 + t * 4]) = ov;
}

// ---- layer-1 aggregation: inline edge weights + bias + residual -----------
__global__ __launch_bounds__(256) void agg1_kernel(
    const ushort* __restrict__ h1,   // [N,128] bf16
    const float* __restrict__ ss, const float* __restrict__ sd,  // [N]
    const int* __restrict__ rowptr, const unsigned* __restrict__ csrSD,
    const float* __restrict__ b1, const float2* __restrict__ x,
    float2* __restrict__ out) {
  const int n = blockIdx.x * 4 + (threadIdx.x >> 6);
  const int t = threadIdx.x & 63;
  const float sdn = sd[n];
  float a0 = 0.f, a1 = 0.f, den = 0.f;
  int p = rowptr[n];
  const int p1 = rowptr[n + 1];
  for (; p + 4 <= p1; p += 4) {
    int s[4];
#pragma unroll
    for (int j = 0; j < 4; ++j) s[j] = (int)(csrSD[p + j] & 0xFFFFu);
    ushort2 v[4];
#pragma unroll
    for (int j = 0; j < 4; ++j)
      v[j] = *reinterpret_cast<const ushort2*>(&h1[(size_t)s[j] * 128 + t * 2]);
    float w[4];
#pragma unroll
    for (int j = 0; j < 4; ++j) {
      float e = ss[s[j]] + sdn;
      e = (e > 0.f) ? e : NEG_SLOPE * e;
      w[j] = __expf(e);
    }
#pragma unroll
    for (int j = 0; j < 4; ++j) {
      den += w[j];
      a0 = fmaf(w[j], bf2f(v[j].x), a0);
      a1 = fmaf(w[j], bf2f(v[j].y), a1);
    }
  }
  for (; p < p1; ++p) {
    const int sj = (int)(csrSD[p] & 0xFFFFu);
    float e = ss[sj] + sdn;
    e = (e > 0.f) ? e : NEG_SLOPE * e;
    const float wj = __expf(e);
    const ushort2 vj = *reinterpret_cast<const ushort2*>(&h1[(size_t)sj * 128 + t * 2]);
    den += wj;
    a0 = fmaf(wj, bf2f(vj.x), a0);
    a1 = fmaf(wj, bf2f(vj.y), a1);
  }
  const float inv = 1.f / den;
  const float2 bv = reinterpret_cast<const float2*>(b1)[t];
  const float2 xv = x[(size_t)n * 64 + t];
  out[(size_t)n * 64 + t] =
      make_float2(xv.x + fmaf(a0, inv, bv.x), xv.y + fmaf(a1, inv, bv.y));
}

extern "C" void kernel_launch(void* const* d_in, const int* in_sizes, int n_in,
                              void* d_out, int out_size, void* d_ws, size_t ws_size,
                              hipStream_t stream) {
  const float* x      = (const float*)d_in[0];
  const float* W0     = (const float*)d_in[1];
  const float* a_src0 = (const float*)d_in[2];
  const float* a_dst0 = (const float*)d_in[3];
  const float* b0     = (const float*)d_in[4];
  const float* W1     = (const float*)d_in[5];
  const float* a_src1 = (const float*)d_in[6];
  const float* a_dst1 = (const float*)d_in[7];
  const float* b1     = (const float*)d_in[8];
  const int*   ei     = (const int*)d_in[9];
  const int E = in_sizes[9] / 2;
  const int Etot = E + N_NODES;
  float* out = (float*)d_out;
  (void)n_in; (void)out_size; (void)ws_size;

  char* ws = (char*)d_ws;
  size_t off = 0;
  auto alloc = [&](size_t bytes) -> char* {
    char* p = ws + off;
    off += (bytes + 255) & ~(size_t)255;
    return p;
  };
  ushort* h0b  = (ushort*)alloc((size_t)N_NODES * 256 * 2);
  ushort* hEb  = (ushort*)alloc((size_t)N_NODES * 256 * 2);
  ushort* h1b  = (ushort*)alloc((size_t)N_NODES * 128 * 2);
  ushort* W0T  = (ushort*)alloc((size_t)256 * 128 * 2);
  ushort* W1T  = (ushort*)alloc((size_t)128 * 256 * 2);
  int* counts  = (int*)alloc((size_t)N_NODES * 4);      // zero-init below
  float* ss0   = (float*)alloc((size_t)N_NODES * 2 * 4);  // direct-stored
  float* sd0   = (float*)alloc((size_t)N_NODES * 2 * 4);
  float* ss1   = (float*)alloc((size_t)N_NODES * 4);
  float* sd1   = (float*)alloc((size_t)N_NODES * 4);
  int* rowptr  = (int*)alloc((size_t)(N_NODES + 1) * 4);
  int* partial = (int*)alloc((size_t)N_NODES * 4);
  int* bsums   = (int*)alloc((size_t)64 * 4);
  ushort* rank = (ushort*)alloc((size_t)Etot * 2);
  unsigned* csrSD = (unsigned*)alloc((size_t)Etot * 4);

  hipMemsetAsync(counts, 0, (size_t)N_NODES * 4, stream);

  // ---- prep: weight transposes (one kernel) ----
  convT2_kernel<<<65536 / 256, 256, 0, stream>>>(W0, W0T, W1, W1T);

  // ---- CSR build (shared by both layers) ----
  const int nblk = (N_NODES + 1023) / 1024;  // 49
  hist_kernel<<<(Etot + 255) / 256, 256, 0, stream>>>(ei, E, Etot, counts, rank);
  scan1_kernel<<<nblk, 1024, 0, stream>>>(counts, partial, bsums, N_NODES);
  scan23_kernel<<<(N_NODES + 255) / 256, 256, 0, stream>>>(partial, bsums, rowptr,
                                                           N_NODES, nblk);
  scatter_kernel<<<(Etot + 255) / 256, 256, 0, stream>>>(ei, E, Etot, rowptr, rank, csrSD);

  // ---- layer 0 (x converted fp32->bf16 inside gemm staging) ----
  dim3 g0(2, (N_NODES + 63) / 64);
  gemm_mfma<2, true><<<g0, 256, 0, stream>>>(x, W0T, h0b, N_NODES, 256, 128,
                                             a_src0, a_dst0, ss0, sd0);
  agg0_kernel<<<N_NODES / 4, 256, 0, stream>>>(h0b, ss0, sd0, rowptr, csrSD, b0, hEb);

  // ---- layer 1 ----
  dim3 g1(1, (N_NODES + 63) / 64);
  gemm_mfma<1, false><<<g1, 256, 0, stream>>>(hEb, W1T, h1b, N_NODES, 128, 256,
                                              a_src1, a_dst1, ss1, sd1);
  agg1_kernel<<<N_NODES / 4, 256, 0, stream>>>(h1b, ss1, sd1, rowptr, csrSD, b1,
                                               (const float2*)x, (float2*)out);
}

// Round 13
// 283.538 us; speedup vs baseline: 1.0870x; 1.0182x over previous
//
#include <hip/hip_runtime.h>

#define N_NODES 50000
#define NEG_SLOPE 0.2f

typedef short s8v __attribute__((ext_vector_type(8)));
typedef float f4v __attribute__((ext_vector_type(4)));

// ---- bf16 helpers (RNE) ---------------------------------------------------
__device__ __forceinline__ ushort f2bf(float f) {
  union { float f; unsigned u; } v; v.f = f;
  return (ushort)((v.u + 0x7FFFu + ((v.u >> 16) & 1u)) >> 16);
}
__device__ __forceinline__ float bf2f(ushort h) {
  union { unsigned u; float f; } v; v.u = ((unsigned)h) << 16;
  return v.f;
}

// ---- both weight transposes in one kernel ---------------------------------
__global__ void convT2_kernel(const float* __restrict__ W0, ushort* __restrict__ W0T,
                              const float* __restrict__ W1, ushort* __restrict__ W1T) {
  int i = blockIdx.x * blockDim.x + threadIdx.x;
  if (i < 32768) {
    int r = i >> 8, c = i & 255;           // W0: R=128, C=256
    W0T[c * 128 + r] = f2bf(W0[i]);
  } else {
    int j = i - 32768;
    int r = j >> 7, c = j & 127;           // W1: R=256, C=128
    W1T[c * 256 + r] = f2bf(W1[j]);
  }
}

// ---- MFMA GEMM, 64M x 128N tile + direct-store attention scores -----------
// R8/R10-proven structure — DO NOT restructure (R9's rewrite was flaky).
template <int HEADS, bool AF32>
__global__ __launch_bounds__(256) void gemm_mfma(
    const void* __restrict__ Av, const ushort* __restrict__ BT,
    ushort* __restrict__ C, int M, int N, int K,
    const float* __restrict__ a_src, const float* __restrict__ a_dst,
    float* __restrict__ ss, float* __restrict__ sd) {
  __shared__ ushort As[64][136];   // +8 pad: 16B-aligned, 2-way banks (free)
  __shared__ ushort Bs[128][136];
  const int tid = threadIdx.x;
  const int w = tid >> 6, lane = tid & 63;
  const int q = lane >> 4, r16 = lane & 15;
  const int n0 = blockIdx.x * 128, m0 = blockIdx.y * 64;
  f4v acc[8] = {};
  for (int kc = 0; kc < K; kc += 128) {
#pragma unroll
    for (int i = 0; i < 4; ++i) {
      int c = tid + 256 * i;
      int row = c >> 4, ko = (c & 15) * 8;
      int gm = m0 + row;
      s8v va = {};
      if (gm < M) {
        if (AF32) {
          const float* A = (const float*)Av;
          float4 f0 = *reinterpret_cast<const float4*>(&A[(size_t)gm * K + kc + ko]);
          float4 f1 = *reinterpret_cast<const float4*>(&A[(size_t)gm * K + kc + ko + 4]);
          va[0] = (short)f2bf(f0.x); va[1] = (short)f2bf(f0.y);
          va[2] = (short)f2bf(f0.z); va[3] = (short)f2bf(f0.w);
          va[4] = (short)f2bf(f1.x); va[5] = (short)f2bf(f1.y);
          va[6] = (short)f2bf(f1.z); va[7] = (short)f2bf(f1.w);
        } else {
          const ushort* A = (const ushort*)Av;
          va = *reinterpret_cast<const s8v*>(&A[(size_t)gm * K + kc + ko]);
        }
      }
      *reinterpret_cast<s8v*>(&As[row][ko]) = va;
    }
#pragma unroll
    for (int i = 0; i < 8; ++i) {
      int c = tid + 256 * i;
      int row = c >> 4, ko = (c & 15) * 8;
      s8v vb = *reinterpret_cast<const s8v*>(&BT[(size_t)(n0 + row) * K + kc + ko]);
      *reinterpret_cast<s8v*>(&Bs[row][ko]) = vb;
    }
    __syncthreads();
#pragma unroll
    for (int ks = 0; ks < 4; ++ks) {
      s8v af = *reinterpret_cast<const s8v*>(&As[w * 16 + r16][ks * 32 + q * 8]);
#pragma unroll
      for (int nt = 0; nt < 8; ++nt) {
        s8v bf = *reinterpret_cast<const s8v*>(&Bs[nt * 16 + r16][ks * 32 + q * 8]);
        acc[nt] = __builtin_amdgcn_mfma_f32_16x16x32_bf16(af, bf, acc[nt], 0, 0, 0);
      }
    }
    __syncthreads();
  }
#pragma unroll
  for (int nt = 0; nt < 8; ++nt)
#pragma unroll
    for (int r = 0; r < 4; ++r) {
      int gm = m0 + w * 16 + q * 4 + r;
      if (gm < M) C[(size_t)gm * N + n0 + nt * 16 + r16] = f2bf(acc[nt][r]);
    }
  const int head = n0 >> 7;
  float ps[4] = {0.f, 0.f, 0.f, 0.f}, pd[4] = {0.f, 0.f, 0.f, 0.f};
#pragma unroll
  for (int nt = 0; nt < 8; ++nt) {
    int n = n0 + nt * 16 + r16;
    float as = a_src[n], ad = a_dst[n];
#pragma unroll
    for (int r = 0; r < 4; ++r) {
      ps[r] = fmaf(acc[nt][r], as, ps[r]);
      pd[r] = fmaf(acc[nt][r], ad, pd[r]);
    }
  }
#pragma unroll
  for (int off = 1; off < 16; off <<= 1) {
#pragma unroll
    for (int r = 0; r < 4; ++r) {
      ps[r] += __shfl_xor(ps[r], off);
      pd[r] += __shfl_xor(pd[r], off);
    }
  }
  if (r16 == 0) {
#pragma unroll
    for (int r = 0; r < 4; ++r) {
      int gm = m0 + w * 16 + q * 4 + r;
      if (gm < M) {
        ss[gm * HEADS + head] = ps[r];
        sd[gm * HEADS + head] = pd[r];
      }
    }
  }
}

// ---- FUSED: layer-0 GEMM + CSR scatter in one dispatch --------------------
// gemm blocks (1564) and scatter blocks (nS) are INDEPENDENT (scatter's
// inputs rowptr/rank are complete before launch; gemm writes h0b/ss0/sd0).
// Interleave 1 gemm : 2 scatter in dispatch order for per-CU co-residency
// (MFMA pipe + memory pipe overlap; m114). gemm body verbatim from template.
#define NG0 1564  // 2 * ceil(N_NODES/64)
__global__ __launch_bounds__(256) void gemm0_scatter_kernel(
    const float* __restrict__ A, const ushort* __restrict__ BT,
    ushort* __restrict__ C, int M,
    const float* __restrict__ a_src, const float* __restrict__ a_dst,
    float* __restrict__ ss, float* __restrict__ sd,
    const int* __restrict__ ei, int E, int Etot, int nS,
    const int* __restrict__ rowptr, const ushort* __restrict__ rank,
    unsigned* __restrict__ csrSD) {
  __shared__ ushort As[64][136];
  __shared__ ushort Bs[128][136];
  const int id = blockIdx.x;
  int gemmIdx = -1, sIdx = -1;
  if (id < 3 * NG0) {
    const int g = id / 3, r = id % 3;
    if (r == 0) gemmIdx = g;
    else        sIdx = 2 * g + (r - 1);
  } else {
    sIdx = 2 * NG0 + (id - 3 * NG0);
  }

  if (gemmIdx >= 0) {
    // ---- gemm body (HEADS=2, AF32, N=256, K=128), x-major block order ----
    const int nb = gemmIdx & 1, mb = gemmIdx >> 1;
    const int tid = threadIdx.x;
    const int w = tid >> 6, lane = tid & 63;
    const int q = lane >> 4, r16 = lane & 15;
    const int n0 = nb * 128, m0 = mb * 64;
    const int N = 256, K = 128;
    f4v acc[8] = {};
    for (int kc = 0; kc < K; kc += 128) {
#pragma unroll
      for (int i = 0; i < 4; ++i) {
        int c = tid + 256 * i;
        int row = c >> 4, ko = (c & 15) * 8;
        int gm = m0 + row;
        s8v va = {};
        if (gm < M) {
          float4 f0 = *reinterpret_cast<const float4*>(&A[(size_t)gm * K + kc + ko]);
          float4 f1 = *reinterpret_cast<const float4*>(&A[(size_t)gm * K + kc + ko + 4]);
          va[0] = (short)f2bf(f0.x); va[1] = (short)f2bf(f0.y);
          va[2] = (short)f2bf(f0.z); va[3] = (short)f2bf(f0.w);
          va[4] = (short)f2bf(f1.x); va[5] = (short)f2bf(f1.y);
          va[6] = (short)f2bf(f1.z); va[7] = (short)f2bf(f1.w);
        }
        *reinterpret_cast<s8v*>(&As[row][ko]) = va;
      }
#pragma unroll
      for (int i = 0; i < 8; ++i) {
        int c = tid + 256 * i;
        int row = c >> 4, ko = (c & 15) * 8;
        s8v vb = *reinterpret_cast<const s8v*>(&BT[(size_t)(n0 + row) * K + kc + ko]);
        *reinterpret_cast<s8v*>(&Bs[row][ko]) = vb;
      }
      __syncthreads();
#pragma unroll
      for (int ks = 0; ks < 4; ++ks) {
        s8v af = *reinterpret_cast<const s8v*>(&As[w * 16 + r16][ks * 32 + q * 8]);
#pragma unroll
        for (int nt = 0; nt < 8; ++nt) {
          s8v bf = *reinterpret_cast<const s8v*>(&Bs[nt * 16 + r16][ks * 32 + q * 8]);
          acc[nt] = __builtin_amdgcn_mfma_f32_16x16x32_bf16(af, bf, acc[nt], 0, 0, 0);
        }
      }
      __syncthreads();
    }
#pragma unroll
    for (int nt = 0; nt < 8; ++nt)
#pragma unroll
      for (int r = 0; r < 4; ++r) {
        int gm = m0 + w * 16 + q * 4 + r;
        if (gm < M) C[(size_t)gm * N + n0 + nt * 16 + r16] = f2bf(acc[nt][r]);
      }
    const int head = n0 >> 7;
    float ps[4] = {0.f, 0.f, 0.f, 0.f}, pd[4] = {0.f, 0.f, 0.f, 0.f};
#pragma unroll
    for (int nt = 0; nt < 8; ++nt) {
      int n = n0 + nt * 16 + r16;
      float as = a_src[n], ad = a_dst[n];
#pragma unroll
      for (int r = 0; r < 4; ++r) {
        ps[r] = fmaf(acc[nt][r], as, ps[r]);
        pd[r] = fmaf(acc[nt][r], ad, pd[r]);
      }
    }
#pragma unroll
    for (int off = 1; off < 16; off <<= 1) {
#pragma unroll
      for (int r = 0; r < 4; ++r) {
        ps[r] += __shfl_xor(ps[r], off);
        pd[r] += __shfl_xor(pd[r], off);
      }
    }
    if (r16 == 0) {
#pragma unroll
      for (int r = 0; r < 4; ++r) {
        int gm = m0 + w * 16 + q * 4 + r;
        if (gm < M) {
          ss[gm * 2 + head] = ps[r];
          sd[gm * 2 + head] = pd[r];
        }
      }
    }
  } else {
    // ---- scatter body (verbatim from R12's scatter_kernel) ----
    if (sIdx >= nS) return;
    int e = sIdx * 256 + threadIdx.x;
    if (e >= Etot) return;
    int s, d;
    if (e < E) { s = ei[e]; d = ei[E + e]; } else { s = d = e - E; }
    csrSD[rowptr[d] + (int)rank[e]] = (unsigned)s | ((unsigned)d << 16);
  }
}

// ------------- CSR build: hist(+u16 rank) -> scan1 -> scan23 ---------------
__global__ void hist_kernel(const int* __restrict__ ei, int E, int Etot,
                            int* __restrict__ counts, ushort* __restrict__ rank) {
  int e = blockIdx.x * blockDim.x + threadIdx.x;
  if (e >= Etot) return;
  int d = (e < E) ? ei[E + e] : (e - E);
  rank[e] = (ushort)atomicAdd(&counts[d], 1);  // degree << 65536
}

__global__ __launch_bounds__(1024) void scan1_kernel(const int* __restrict__ counts,
                                                     int* __restrict__ partial,
                                                     int* __restrict__ blocksums, int n) {
  __shared__ int tmp[1024];
  int i = blockIdx.x * 1024 + threadIdx.x;
  int v = (i < n) ? counts[i] : 0;
  tmp[threadIdx.x] = v;
  __syncthreads();
  for (int off = 1; off < 1024; off <<= 1) {
    int t = (threadIdx.x >= off) ? tmp[threadIdx.x - off] : 0;
    __syncthreads();
    tmp[threadIdx.x] += t;
    __syncthreads();
  }
  if (i < n) partial[i] = tmp[threadIdx.x];
  if (threadIdx.x == 1023) blocksums[blockIdx.x] = tmp[1023];
}

__global__ void scan23_kernel(const int* __restrict__ partial,
                              const int* __restrict__ blocksums,
                              int* __restrict__ rowptr, int n, int nb) {
  __shared__ int sb[64];
  int t = threadIdx.x;
  if (t < 64) {
    int v = (t < nb) ? blocksums[t] : 0;
#pragma unroll
    for (int off = 1; off < 64; off <<= 1) {
      int u = __shfl_up(v, off);
      if ((t & 63) >= off) v += u;
    }
    sb[t] = v;
  }
  __syncthreads();
  int i = blockIdx.x * blockDim.x + t;
  if (i == 0) rowptr[0] = 0;
  if (i < n) {
    int b = i >> 10;
    int add = (b > 0) ? sb[b - 1] : 0;
    rowptr[i + 1] = partial[i] + add;
  }
}

// ---- layer-0 aggregation: whole-row wave, inline weights (R12-proven) -----
__global__ __launch_bounds__(256) void agg0_kernel(
    const ushort* __restrict__ h0,   // [N,256] bf16
    const float* __restrict__ ss, const float* __restrict__ sd,  // [N,2]
    const int* __restrict__ rowptr, const unsigned* __restrict__ csrSD,
    const float* __restrict__ b0, ushort* __restrict__ hE) {
  const int n = blockIdx.x * 4 + (threadIdx.x >> 6);
  const int t = threadIdx.x & 63;
  const int hd = t >> 5;
  const float sdn = sd[n * 2 + hd];
  float a0 = 0.f, a1 = 0.f, a2 = 0.f, a3 = 0.f, den = 0.f;
  int p = rowptr[n];
  const int p1 = rowptr[n + 1];
  for (; p + 4 <= p1; p += 4) {  // 4 rows in flight per wave
    int s[4];
#pragma unroll
    for (int j = 0; j < 4; ++j) s[j] = (int)(csrSD[p + j] & 0xFFFFu);
    ushort4 v[4];
#pragma unroll
    for (int j = 0; j < 4; ++j)
      v[j] = *reinterpret_cast<const ushort4*>(&h0[(size_t)s[j] * 256 + t * 4]);
    float w[4];
#pragma unroll
    for (int j = 0; j < 4; ++j) {
      float e = ss[s[j] * 2 + hd] + sdn;
      e = (e > 0.f) ? e : NEG_SLOPE * e;
      w[j] = __expf(e);
    }
#pragma unroll
    for (int j = 0; j < 4; ++j) {
      den += w[j];
      a0 = fmaf(w[j], bf2f(v[j].x), a0);
      a1 = fmaf(w[j], bf2f(v[j].y), a1);
      a2 = fmaf(w[j], bf2f(v[j].z), a2);
      a3 = fmaf(w[j], bf2f(v[j].w), a3);
    }
  }
  for (; p < p1; ++p) {
    const int sj = (int)(csrSD[p] & 0xFFFFu);
    float e = ss[sj * 2 + hd] + sdn;
    e = (e > 0.f) ? e : NEG_SLOPE * e;
    const float wj = __expf(e);
    const ushort4 vj = *reinterpret_cast<const ushort4*>(&h0[(size_t)sj * 256 + t * 4]);
    den += wj;
    a0 = fmaf(wj, bf2f(vj.x), a0); a1 = fmaf(wj, bf2f(vj.y), a1);
    a2 = fmaf(wj, bf2f(vj.z), a2); a3 = fmaf(wj, bf2f(vj.w), a3);
  }
  const float inv = 1.f / den;
  const float4 bv = reinterpret_cast<const float4*>(b0)[t];
  float o[4] = {fmaf(a0, inv, bv.x), fmaf(a1, inv, bv.y),
                fmaf(a2, inv, bv.z), fmaf(a3, inv, bv.w)};
#pragma unroll
  for (int i = 0; i < 4; ++i) o[i] = (o[i] > 0.f) ? o[i] : (__expf(o[i]) - 1.f);
  ushort4 ov; ov.x = f2bf(o[0]); ov.y = f2bf(o[1]); ov.z = f2bf(o[2]); ov.w = f2bf(o[3]);
  *reinterpret_cast<ushort4*>(&hE[(size_t)n * 256 + t * 4]) = ov;
}

// ---- layer-1 aggregation: inline edge weights + bias + residual -----------
__global__ __launch_bounds__(256) void agg1_kernel(
    const ushort* __restrict__ h1,   // [N,128] bf16
    const float* __restrict__ ss, const float* __restrict__ sd,  // [N]
    const int* __restrict__ rowptr, const unsigned* __restrict__ csrSD,
    const float* __restrict__ b1, const float2* __restrict__ x,
    float2* __restrict__ out) {
  const int n = blockIdx.x * 4 + (threadIdx.x >> 6);
  const int t = threadIdx.x & 63;
  const float sdn = sd[n];
  float a0 = 0.f, a1 = 0.f, den = 0.f;
  int p = rowptr[n];
  const int p1 = rowptr[n + 1];
  for (; p + 4 <= p1; p += 4) {
    int s[4];
#pragma unroll
    for (int j = 0; j < 4; ++j) s[j] = (int)(csrSD[p + j] & 0xFFFFu);
    ushort2 v[4];
#pragma unroll
    for (int j = 0; j < 4; ++j)
      v[j] = *reinterpret_cast<const ushort2*>(&h1[(size_t)s[j] * 128 + t * 2]);
    float w[4];
#pragma unroll
    for (int j = 0; j < 4; ++j) {
      float e = ss[s[j]] + sdn;
      e = (e > 0.f) ? e : NEG_SLOPE * e;
      w[j] = __expf(e);
    }
#pragma unroll
    for (int j = 0; j < 4; ++j) {
      den += w[j];
      a0 = fmaf(w[j], bf2f(v[j].x), a0);
      a1 = fmaf(w[j], bf2f(v[j].y), a1);
    }
  }
  for (; p < p1; ++p) {
    const int sj = (int)(csrSD[p] & 0xFFFFu);
    float e = ss[sj] + sdn;
    e = (e > 0.f) ? e : NEG_SLOPE * e;
    const float wj = __expf(e);
    const ushort2 vj = *reinterpret_cast<const ushort2*>(&h1[(size_t)sj * 128 + t * 2]);
    den += wj;
    a0 = fmaf(wj, bf2f(vj.x), a0);
    a1 = fmaf(wj, bf2f(vj.y), a1);
  }
  const float inv = 1.f / den;
  const float2 bv = reinterpret_cast<const float2*>(b1)[t];
  const float2 xv = x[(size_t)n * 64 + t];
  out[(size_t)n * 64 + t] =
      make_float2(xv.x + fmaf(a0, inv, bv.x), xv.y + fmaf(a1, inv, bv.y));
}

extern "C" void kernel_launch(void* const* d_in, const int* in_sizes, int n_in,
                              void* d_out, int out_size, void* d_ws, size_t ws_size,
                              hipStream_t stream) {
  const float* x      = (const float*)d_in[0];
  const float* W0     = (const float*)d_in[1];
  const float* a_src0 = (const float*)d_in[2];
  const float* a_dst0 = (const float*)d_in[3];
  const float* b0     = (const float*)d_in[4];
  const float* W1     = (const float*)d_in[5];
  const float* a_src1 = (const float*)d_in[6];
  const float* a_dst1 = (const float*)d_in[7];
  const float* b1     = (const float*)d_in[8];
  const int*   ei     = (const int*)d_in[9];
  const int E = in_sizes[9] / 2;
  const int Etot = E + N_NODES;
  float* out = (float*)d_out;
  (void)n_in; (void)out_size; (void)ws_size;

  char* ws = (char*)d_ws;
  size_t off = 0;
  auto alloc = [&](size_t bytes) -> char* {
    char* p = ws + off;
    off += (bytes + 255) & ~(size_t)255;
    return p;
  };
  ushort* h0b  = (ushort*)alloc((size_t)N_NODES * 256 * 2);
  ushort* hEb  = (ushort*)alloc((size_t)N_NODES * 256 * 2);
  ushort* h1b  = (ushort*)alloc((size_t)N_NODES * 128 * 2);
  ushort* W0T  = (ushort*)alloc((size_t)256 * 128 * 2);
  ushort* W1T  = (ushort*)alloc((size_t)128 * 256 * 2);
  int* counts  = (int*)alloc((size_t)N_NODES * 4);      // zero-init below
  float* ss0   = (float*)alloc((size_t)N_NODES * 2 * 4);  // direct-stored
  float* sd0   = (float*)alloc((size_t)N_NODES * 2 * 4);
  float* ss1   = (float*)alloc((size_t)N_NODES * 4);
  float* sd1   = (float*)alloc((size_t)N_NODES * 4);
  int* rowptr  = (int*)alloc((size_t)(N_NODES + 1) * 4);
  int* partial = (int*)alloc((size_t)N_NODES * 4);
  int* bsums   = (int*)alloc((size_t)64 * 4);
  ushort* rank = (ushort*)alloc((size_t)Etot * 2);
  unsigned* csrSD = (unsigned*)alloc((size_t)Etot * 4);

  hipMemsetAsync(counts, 0, (size_t)N_NODES * 4, stream);

  // ---- prep: weight transposes (one kernel) ----
  convT2_kernel<<<65536 / 256, 256, 0, stream>>>(W0, W0T, W1, W1T);

  // ---- CSR build, phase 1: hist + scans (scatter fused below) ----
  const int nblk = (N_NODES + 1023) / 1024;  // 49
  hist_kernel<<<(Etot + 255) / 256, 256, 0, stream>>>(ei, E, Etot, counts, rank);
  scan1_kernel<<<nblk, 1024, 0, stream>>>(counts, partial, bsums, N_NODES);
  scan23_kernel<<<(N_NODES + 255) / 256, 256, 0, stream>>>(partial, bsums, rowptr,
                                                           N_NODES, nblk);

  // ---- FUSED: layer-0 gemm (1564 blocks) + scatter (nS blocks) ----
  const int nS = (Etot + 255) / 256;
  const int grid = 3 * NG0 + ((nS > 2 * NG0) ? (nS - 2 * NG0) : 0);
  gemm0_scatter_kernel<<<grid, 256, 0, stream>>>(
      x, W0T, h0b, N_NODES, a_src0, a_dst0, ss0, sd0,
      ei, E, Etot, nS, rowptr, rank, csrSD);

  agg0_kernel<<<N_NODES / 4, 256, 0, stream>>>(h0b, ss0, sd0, rowptr, csrSD, b0, hEb);

  // ---- layer 1 ----
  dim3 g1(1, (N_NODES + 63) / 64);
  gemm_mfma<1, false><<<g1, 256, 0, stream>>>(hEb, W1T, h1b, N_NODES, 128, 256,
                                              a_src1, a_dst1, ss1, sd1);
  agg1_kernel<<<N_NODES / 4, 256, 0, stream>>>(h1b, ss1, sd1, rowptr, csrSD, b1,
                                               (const float2*)x, (float2*)out);
}